// Round 17
// baseline (197.809 us; speedup 1.0000x reference)
//
#include <hip/hip_runtime.h>
#include <hip/hip_bf16.h>

#define B_ 4
#define L_ 1024
#define D_ 1024
#define H_ 16
#define NROWS_ (B_ * L_)   // 4096

typedef __attribute__((ext_vector_type(8))) short short8;
typedef __attribute__((ext_vector_type(4))) float f32x4;

__device__ __forceinline__ ushort f2bf(float f) {   // native RNE cvt (single VALU op)
    __hip_bfloat16 h = __float2bfloat16(f);
    return *reinterpret_cast<ushort*>(&h);
}
__device__ __forceinline__ float bf2f(ushort u) {
    union { uint u; float f; } x; x.u = (uint)u << 16; return x.f;
}
__device__ __forceinline__ void gl_lds16(const void* g, void* l) {
    __builtin_amdgcn_global_load_lds(
        (const __attribute__((address_space(1))) uint*)(uintptr_t)g,
        (__attribute__((address_space(3))) uint*)(uintptr_t)l, 16, 0, 0);
}

#define EXP2C 0.1803368801111244f   // 0.125 * log2(e), baked into qh projection

// ---------------- fused LayerNorm->bf16  +  weight cvt ----------------
__global__ __launch_bounds__(256) void lnwcvt_kernel(
    const float* __restrict__ q, const float* __restrict__ k, const float* __restrict__ v,
    const float* __restrict__ ln1w, const float* __restrict__ ln1b,
    const float* __restrict__ ln2w, const float* __restrict__ ln2b,
    const float* __restrict__ ln3w, const float* __restrict__ ln3b,
    ushort* __restrict__ qn, ushort* __restrict__ kn, ushort* __restrict__ vn,
    const float* __restrict__ wq, const float* __restrict__ wk,
    const float* __restrict__ wv, const float* __restrict__ wfc,
    ushort* __restrict__ wqb, ushort* __restrict__ wkb,
    ushort* __restrict__ wvb, ushort* __restrict__ wfcb)
{
    const int bid = blockIdx.x, t = threadIdx.x;
    if (bid >= 12288) {   // weight convert (read-once: NT loads via ext_vector)
        const int wbid = bid - 12288;
        const int which = wbid >> 10;
        const float* src = which == 0 ? wq : which == 1 ? wk : which == 2 ? wv : wfc;
        ushort* dst      = which == 0 ? wqb : which == 1 ? wkb : which == 2 ? wvb : wfcb;
        const size_t i = (size_t)(wbid & 1023) * 256 + t;
        const f32x4 f = __builtin_nontemporal_load(&((const f32x4*)src)[i]);
        ushort4 o; o.x = f2bf(f[0]); o.y = f2bf(f[1]); o.z = f2bf(f[2]); o.w = f2bf(f[3]);
        ((ushort4*)dst)[i] = o;
        return;
    }
    const int which = bid >> 12, row = bid & 4095;
    const float *x, *lw, *lb; ushort* out;
    if (which == 0)      { x = q; lw = ln1w; lb = ln1b; out = qn; }
    else if (which == 1) { x = k; lw = ln2w; lb = ln2b; out = kn; }
    else                 { x = v; lw = ln3w; lb = ln3b; out = vn; }
    x += (size_t)row * D_; out += (size_t)row * D_;
    const f32x4 t4 = __builtin_nontemporal_load(&((const f32x4*)x)[t]);
    float s  = t4[0] + t4[1] + t4[2] + t4[3];
    float s2 = t4[0]*t4[0] + t4[1]*t4[1] + t4[2]*t4[2] + t4[3]*t4[3];
    #pragma unroll
    for (int off = 1; off < 64; off <<= 1) {
        s  += __shfl_xor(s,  off, 64);
        s2 += __shfl_xor(s2, off, 64);
    }
    __shared__ float red[8];
    __shared__ float mr[2];
    const int wid = t >> 6;
    if ((t & 63) == 0) { red[wid*2] = s; red[wid*2+1] = s2; }
    __syncthreads();
    if (t == 0) {
        s  = red[0] + red[2] + red[4] + red[6];
        s2 = red[1] + red[3] + red[5] + red[7];
        const float mean = s * (1.0f/(float)D_);
        const float var  = s2 * (1.0f/(float)D_) - mean*mean;
        mr[0] = mean; mr[1] = rsqrtf(var + 1e-5f);
    }
    __syncthreads();
    const float mean = mr[0], rstd = mr[1];
    const float4 w4 = ((const float4*)lw)[t];
    const float4 b4 = ((const float4*)lb)[t];
    ushort4 o;
    o.x = f2bf((t4[0] - mean)*rstd*w4.x + b4.x);
    o.y = f2bf((t4[1] - mean)*rstd*w4.y + b4.y);
    o.z = f2bf((t4[2] - mean)*rstd*w4.z + b4.z);
    o.w = f2bf((t4[3] - mean)*rstd*w4.w + b4.w);
    ((ushort4*)out)[t] = o;
}

// ---------------- fused mask gather (first!) + 3-way projection GEMM ----------------
// gid < 256: mask->gbits gather (dispatches FIRST, hides under GEMM compute)
// gid >= 256: GEMMs (z = (gid-256)%3)
__global__ __launch_bounds__(256) void projgather_kernel(
    const ushort* __restrict__ qn, const ushort* __restrict__ kn, const ushort* __restrict__ vn,
    const ushort* __restrict__ wqb, const ushort* __restrict__ wkb, const ushort* __restrict__ wvb,
    ushort* __restrict__ qh, ushort* __restrict__ kh, ushort* __restrict__ vtw,
    const int* __restrict__ mask, uint2* __restrict__ gbits)
{
    const int gid = blockIdx.x;
    const int t = threadIdx.x;
    if (gid < 256) {    // mask gather: 16 rows per block
        const int row = gid * 16 + (t >> 4);
        const int lc = t & 15;
        const int* src = mask + (size_t)row * 1024 + lc;
        uint lo = 0, hi = 0;
        #pragma unroll
        for (int j = 0; j < 32; j++) lo |= (__builtin_nontemporal_load(&src[16*j])      != 0 ? 1u : 0u) << j;
        #pragma unroll
        for (int j = 0; j < 32; j++) hi |= (__builtin_nontemporal_load(&src[16*(j+32)]) != 0 ? 1u : 0u) << j;
        gbits[(size_t)row*16 + lc] = make_uint2(lo, hi);
        return;
    }
    __shared__ __align__(16) ushort As[128*64];
    __shared__ __align__(16) ushort Bs[128*64];
    const int gg = gid - 256;
    const int z = gg % 3, id = gg / 3;
    const ushort *A, *W; ushort* out;
    if (z == 0)      { A = qn;  W = wqb; out = qh;  }
    else if (z == 1) { A = kn;  W = wkb; out = kh;  }
    else             { A = wvb; W = vn;  out = vtw; }
    int bm, bn;
    if (z < 2) { bm = (id >> 3) * 128; bn = (id & 7)  * 128; }
    else       { bm = (id >> 5) * 128; bn = (id & 31) * 128; }

    const int w = t >> 6, lane = t & 63;
    const int lc = lane & 15, g = lane >> 4;
    const int wr = w >> 1, wc = w & 1;
    const int srow = lane >> 3, sp = lane & 7;
    f32x4 acc[4][4] = {};

    for (int k0 = 0; k0 < 1024; k0 += 64) {
        #pragma unroll
        for (int j = 0; j < 4; j++) {
            const int i = w*4 + j;
            const int row = i*8 + srow;
            const int c = (sp - (row & 7)) & 7;
            gl_lds16(A + (size_t)(bm+row)*1024 + k0 + c*8, &As[i*512]);
            gl_lds16(W + (size_t)(bn+row)*1024 + k0 + c*8, &Bs[i*512]);
        }
        __syncthreads();
        #pragma unroll
        for (int ks = 0; ks < 2; ks++) {
            short8 af[4], bf4[4];
            #pragma unroll
            for (int mi = 0; mi < 4; mi++) {
                const int row = wr*64 + mi*16 + lc;
                af[mi] = *(const short8*)&As[row*64 + (((ks*4+g) + (row&7)) & 7)*8];
            }
            #pragma unroll
            for (int ni = 0; ni < 4; ni++) {
                const int row = wc*64 + ni*16 + lc;
                bf4[ni] = *(const short8*)&Bs[row*64 + (((ks*4+g) + (row&7)) & 7)*8];
            }
            #pragma unroll
            for (int mi = 0; mi < 4; mi++)
                #pragma unroll
                for (int ni = 0; ni < 4; ni++)
                    acc[mi][ni] = __builtin_amdgcn_mfma_f32_16x16x32_bf16(af[mi], bf4[ni], acc[mi][ni], 0, 0, 0);
        }
        __syncthreads();
    }

    const float scale = (z == 0) ? EXP2C : 1.0f;   // bake softmax scale into qh
    #pragma unroll
    for (int mi = 0; mi < 4; mi++)
        #pragma unroll
        for (int ni = 0; ni < 4; ni++)
            #pragma unroll
            for (int r = 0; r < 4; r++) {
                const int m = bm + wr*64 + mi*16 + g*4 + r;
                const int n = bn + wc*64 + ni*16 + lc;
                const ushort val = f2bf(acc[mi][ni][r] * scale);
                if (z < 2) {
                    const int bb = m >> 10, seq = m & 1023, hh = n >> 6, d = n & 63;
                    out[(((size_t)(bb*16+hh))*1024 + seq)*64 + d] = val;
                } else {
                    const int bb = n >> 10, seq = n & 1023, hh = m >> 6, d = m & 63;
                    out[((size_t)(bb*16+hh))*65536 + (size_t)d*1024 + seq] = val;
                }
            }
}

// ---------------- fc GEMM: 128x64 tile, fp32 NT out ----------------
__global__ __launch_bounds__(256) void fc_kernel(
    const ushort* __restrict__ A, const ushort* __restrict__ W, float* __restrict__ C)
{
    __shared__ __align__(16) ushort As[128*64];
    __shared__ __align__(16) ushort Bs[64*64];
    const int t = threadIdx.x, w = t >> 6, lane = t & 63;
    const int lc = lane & 15, g = lane >> 4;
    const int wr = w >> 1, wc = w & 1;
    const int bm = blockIdx.x * 128, bn = blockIdx.y * 64;
    const int srow = lane >> 3, sp = lane & 7;
    f32x4 acc[4][2] = {};

    for (int k0 = 0; k0 < 1024; k0 += 64) {
        #pragma unroll
        for (int j = 0; j < 4; j++) {
            const int i = w*4 + j;
            const int row = i*8 + srow;
            const int c = (sp - (row & 7)) & 7;
            gl_lds16(A + (size_t)(bm+row)*1024 + k0 + c*8, &As[i*512]);
        }
        #pragma unroll
        for (int j = 0; j < 2; j++) {
            const int i = w*2 + j;
            const int row = i*8 + srow;
            const int c = (sp - (row & 7)) & 7;
            gl_lds16(W + (size_t)(bn+row)*1024 + k0 + c*8, &Bs[i*512]);
        }
        __syncthreads();
        #pragma unroll
        for (int ks = 0; ks < 2; ks++) {
            short8 af[4], bf4[2];
            #pragma unroll
            for (int mi = 0; mi < 4; mi++) {
                const int row = wr*64 + mi*16 + lc;
                af[mi] = *(const short8*)&As[row*64 + (((ks*4+g) + (row&7)) & 7)*8];
            }
            #pragma unroll
            for (int ni = 0; ni < 2; ni++) {
                const int row = wc*32 + ni*16 + lc;
                bf4[ni] = *(const short8*)&Bs[row*64 + (((ks*4+g) + (row&7)) & 7)*8];
            }
            #pragma unroll
            for (int mi = 0; mi < 4; mi++)
                #pragma unroll
                for (int ni = 0; ni < 2; ni++)
                    acc[mi][ni] = __builtin_amdgcn_mfma_f32_16x16x32_bf16(af[mi], bf4[ni], acc[mi][ni], 0, 0, 0);
        }
        __syncthreads();
    }

    #pragma unroll
    for (int mi = 0; mi < 4; mi++)
        #pragma unroll
        for (int ni = 0; ni < 2; ni++)
            #pragma unroll
            for (int r = 0; r < 4; r++)
                __builtin_nontemporal_store(acc[mi][ni][r],
                    &C[(size_t)(bm + wr*64 + mi*16 + g*4 + r)*1024 + bn + wc*32 + ni*16 + lc]);
}

// ---------------- MFMA attention: 8 waves, 128 q-rows/block, XCD-grouped ----------------
// p stored DIRECTLY from fragment registers (each thread owns its values; per-(ni,r)
// dword store = 4x64B fully-covered lines). Pb kept only for the PV A-fragment.
#define AS_VMCNT(N) asm volatile("s_waitcnt vmcnt(" #N ")" ::: "memory")
#define AS_BAR()    asm volatile("s_barrier" ::: "memory")

__global__ __launch_bounds__(512, 4) void attn_kernel(
    const ushort* __restrict__ qh, const ushort* __restrict__ kh, const ushort* __restrict__ vt,
    const uint2* __restrict__ gbits, float* __restrict__ p_out, ushort* __restrict__ ctx)
{
    __shared__ __align__(16) ushort KV[6][64*64];   // [0..2]=K triple buf; [3..5]=V triple buf
    __shared__ __align__(16) ushort Pb[8][16*72];
    const int t = threadIdx.x, w = t >> 6, lane = t & 63;
    const int lc = lane & 15, g = lane >> 4;
    // XCD-aware decode
    const int p = blockIdx.x;
    const int xcd = p & 7, slot = p >> 3;
    const int grp = xcd + 8 * (slot >> 3);       // 0..63
    const int tile = slot & 7;
    const int h = grp & 15, b = grp >> 4;
    const int q0 = tile * 128;
    const int qrow = w * 16;
    const ushort* qbase = qh + ((size_t)(b*16+h)*1024 + q0 + qrow)*64;
    const ushort* kbase = kh + (size_t)(b*16+h)*1024*64;
    const ushort* vbase = vt + (size_t)(b*16+h)*64*1024;
    ushort* PbW = Pb[w];

    // Q fragments (EXP2C pre-baked by projection)
    const short8 aq0 = *(const short8*)(qbase + (size_t)lc*64 + g*8);
    const short8 aq1 = *(const short8*)(qbase + (size_t)lc*64 + 32 + g*8);

    // gathered mask bits: 4 q-rows per thread, bit (kt*4+ni) = masked
    unsigned long long gb[4];
    #pragma unroll
    for (int r = 0; r < 4; r++) {
        const uint2 u = gbits[((size_t)(b*1024 + q0 + qrow + g*4 + r))*16 + lc];
        gb[r] = ((unsigned long long)u.y << 32) | (unsigned long long)u.x;
    }

    // staging geometry
    const int srow = t >> 3;                     // 0..63
    const int sp = t & 7;
    const int c = (sp - (srow & 7)) & 7;

    // prologue: K tile 0 -> KV[0]
    gl_lds16(kbase + (size_t)srow*64 + c*8, &KV[0][w*512]);

    float s_part[4] = {0.f, 0.f, 0.f, 0.f};

    // ---- pass 1: row sums of exp2(S), K triple-buffered, ONE barrier/iter ----
    for (int kt = 0; kt < 16; kt++) {
        const ushort* kcur = KV[kt % 3];
        if (kt < 15) {
            gl_lds16(kbase + ((size_t)((kt+1)*64+srow))*64 + c*8, &KV[(kt+1)%3][w*512]);
            AS_VMCNT(1);
        } else {
            AS_VMCNT(0);
        }
        AS_BAR();
        f32x4 sacc[4];
        __builtin_amdgcn_s_setprio(1);
        #pragma unroll
        for (int ni = 0; ni < 4; ni++) {
            const int row = ni*16 + lc;
            const short8 b0 = *(const short8*)&kcur[row*64 + (((g  ) + (row&7)) & 7)*8];
            const short8 b1 = *(const short8*)&kcur[row*64 + (((4+g) + (row&7)) & 7)*8];
            f32x4 z = {0.f,0.f,0.f,0.f};
            z = __builtin_amdgcn_mfma_f32_16x16x32_bf16(aq0, b0, z, 0, 0, 0);
            z = __builtin_amdgcn_mfma_f32_16x16x32_bf16(aq1, b1, z, 0, 0, 0);
            sacc[ni] = z;
        }
        __builtin_amdgcn_s_setprio(0);
        #pragma unroll
        for (int r = 0; r < 4; r++) {
            const uint mb = (uint)(gb[r] >> (kt*4)) & 15u;   // hoisted nibble
            #pragma unroll
            for (int ni = 0; ni < 4; ni++) {
                const bool mk = (mb >> ni) & 1u;
                s_part[r] += mk ? 0.f : exp2f(sacc[ni][r]);
            }
        }
        // no trailing barrier: 3-buffer distance-2 safety
    }

    // prefetch pass-2 tile 0: K -> KV[1], V -> KV[4]
    gl_lds16(kbase + (size_t)srow*64 + c*8,   &KV[1][w*512]);
    gl_lds16(vbase + (size_t)srow*1024 + c*8, &KV[4][w*512]);

    float inv[4];
    #pragma unroll
    for (int r = 0; r < 4; r++) {
        float s = s_part[r];
        #pragma unroll
        for (int off = 1; off < 16; off <<= 1) s += __shfl_xor(s, off, 64);
        inv[r] = (s > 0.f) ? (1.0f / s) : 0.f;
    }

    // ---- pass 2: Pb holds raw bf16(e) for PV; p stored direct from regs (fp32 e*inv) ----
    f32x4 cacc[4] = {{0,0,0,0},{0,0,0,0},{0,0,0,0},{0,0,0,0}};
    float* pblk = p_out + ((size_t)(h*B_ + b)*1024 + q0 + qrow)*1024;
    for (int kt = 0; kt < 16; kt++) {
        const int kb = (kt + 1) % 3;
        const ushort* kcur = KV[kb];
        const ushort* vcur = KV[3 + kb];
        if (kt < 15) {
            const int nb = (kt + 2) % 3;
            gl_lds16(kbase + ((size_t)((kt+1)*64+srow))*64 + c*8, &KV[nb][w*512]);
            gl_lds16(vbase + (size_t)srow*1024 + (kt+1)*64 + c*8, &KV[3+nb][w*512]);
        }
        // queue at wait (oldest->newest): [L(kt)... retired], S(kt-1)x16 issued after L(kt+1)? no:
        // order per iter: L(kt+1)x2 at top, then S(kt)x16 in body. At this wait:
        // in-flight = L(kt+1)x2 (wait... those were issued THIS iter top) + S(kt-1)x16 + ...
        // kt==0: only prologue L(0)x2 older + L(1)x2 -> need L(0) retired -> vmcnt(2)
        // steady: S(kt-1)x16 older than L(kt+1)x2; need L(kt) retired -> allow 18 -> vmcnt(18)
        // kt==15: no new loads; in-flight L(15)x2? retired check: allow S(14)x16 -> vmcnt(16)
        if (kt == 0) { AS_VMCNT(2); } else if (kt == 15) { AS_VMCNT(16); } else { AS_VMCNT(18); }
        AS_BAR();
        f32x4 sacc[4];
        __builtin_amdgcn_s_setprio(1);
        #pragma unroll
        for (int ni = 0; ni < 4; ni++) {
            const int row = ni*16 + lc;
            const short8 b0 = *(const short8*)&kcur[row*64 + (((g  ) + (row&7)) & 7)*8];
            const short8 b1 = *(const short8*)&kcur[row*64 + (((4+g) + (row&7)) & 7)*8];
            f32x4 z = {0.f,0.f,0.f,0.f};
            z = __builtin_amdgcn_mfma_f32_16x16x32_bf16(aq0, b0, z, 0, 0, 0);
            z = __builtin_amdgcn_mfma_f32_16x16x32_bf16(aq1, b1, z, 0, 0, 0);
            sacc[ni] = z;
        }
        __builtin_amdgcn_s_setprio(0);
        #pragma unroll
        for (int r = 0; r < 4; r++) {
            const uint mb = (uint)(gb[r] >> (kt*4)) & 15u;
            float* prow = pblk + (size_t)(g*4+r)*1024 + kt*64 + lc;
            #pragma unroll
            for (int ni = 0; ni < 4; ni++) {
                const bool mk = (mb >> ni) & 1u;
                const float e = mk ? 0.f : exp2f(sacc[ni][r]);
                PbW[(g*4+r)*72 + ni*16 + lc] = f2bf(e);
                __builtin_nontemporal_store(e * inv[r], prow + ni*16);
            }
        }
        const short8 pa0 = *(const short8*)&PbW[lc*72 + g*8];
        const short8 pa1 = *(const short8*)&PbW[lc*72 + 32 + g*8];
        __builtin_amdgcn_s_setprio(1);
        #pragma unroll
        for (int di = 0; di < 4; di++) {
            const int row = di*16 + lc;
            const short8 vb0 = *(const short8*)&vcur[row*64 + (((g  ) + (row&7)) & 7)*8];
            const short8 vb1 = *(const short8*)&vcur[row*64 + (((4+g) + (row&7)) & 7)*8];
            cacc[di] = __builtin_amdgcn_mfma_f32_16x16x32_bf16(pa0, vb0, cacc[di], 0, 0, 0);
            cacc[di] = __builtin_amdgcn_mfma_f32_16x16x32_bf16(pa1, vb1, cacc[di], 0, 0, 0);
        }
        __builtin_amdgcn_s_setprio(0);
        // no trailing barrier: 3-buffer distance-2 safety
    }

    // ---- ctx epilogue: normalize (PV was on raw e), transpose through PbW ----
    #pragma unroll
    for (int di = 0; di < 4; di++)
        #pragma unroll
        for (int r = 0; r < 4; r++)
            PbW[(g*4+r)*72 + di*16 + lc] = f2bf(cacc[di][r] * inv[r]);
    {
        const int rr = lane >> 2, seg = (lane & 3) * 16;
        const short8 c0 = *(const short8*)&PbW[rr*72 + seg + 0];
        const short8 c1 = *(const short8*)&PbW[rr*72 + seg + 8];
        ushort* dst = ctx + ((size_t)(b*1024 + q0 + qrow + rr))*1024 + h*64 + seg;
        *(short8*)(dst + 0) = c0;
        *(short8*)(dst + 8) = c1;
    }
}

extern "C" void kernel_launch(void* const* d_in, const int* in_sizes, int n_in,
                              void* d_out, int out_size, void* d_ws, size_t ws_size,
                              hipStream_t stream)
{
    const float* q    = (const float*)d_in[0];
    const float* k    = (const float*)d_in[1];
    const float* v    = (const float*)d_in[2];
    const int*   mask = (const int*)d_in[4];
    const float* ln1w = (const float*)d_in[5];
    const float* ln1b = (const float*)d_in[6];
    const float* ln2w = (const float*)d_in[7];
    const float* ln2b = (const float*)d_in[8];
    const float* ln3w = (const float*)d_in[9];
    const float* ln3b = (const float*)d_in[10];
    const float* wq   = (const float*)d_in[11];
    const float* wk   = (const float*)d_in[12];
    const float* wv   = (const float*)d_in[13];
    const float* wfc  = (const float*)d_in[14];

    float* dyn_out  = (float*)d_out;                       // [B, L, D]
    float* attn_out = dyn_out + (size_t)B_ * L_ * D_;      // [H*B, L, L]

    char* ws = (char*)d_ws;
    uint2*  gbits = (uint2*)ws;       ws += (size_t)NROWS_ * 16 * 8;         // 512 KB
    ushort* qn    = (ushort*)ws;      ws += (size_t)NROWS_ * D_ * 2;
    ushort* kn    = (ushort*)ws;      ws += (size_t)NROWS_ * D_ * 2;
    ushort* vn    = (ushort*)ws;      ws += (size_t)NROWS_ * D_ * 2;
    ushort* wqb   = (ushort*)ws;      ws += (size_t)D_ * D_ * 2;
    ushort* wkb   = (ushort*)ws;      ws += (size_t)D_ * D_ * 2;
    ushort* wvb   = (ushort*)ws;      ws += (size_t)D_ * D_ * 2;
    ushort* wfcb  = (ushort*)ws;      ws += (size_t)D_ * D_ * 2;
    ushort* qh    = (ushort*)ws;      ws += (size_t)NROWS_ * D_ * 2;
    ushort* kh    = (ushort*)ws;      ws += (size_t)NROWS_ * D_ * 2;
    ushort* vtw   = (ushort*)ws;      ws += (size_t)NROWS_ * D_ * 2;
    ushort* ctx   = qn;               // qn dead after proj; reuse

    lnwcvt_kernel<<<16384, 256, 0, stream>>>(q, k, v, ln1w, ln1b, ln2w, ln2b, ln3w, ln3b,
                                             qn, kn, vn, wq, wk, wv, wfc, wqb, wkb, wvb, wfcb);

    projgather_kernel<<<1024, 256, 0, stream>>>(qn, kn, vn, wqb, wkb, wvb, qh, kh, vtw, mask, gbits);

    attn_kernel<<<512, 512, 0, stream>>>(qh, kh, vtw, gbits, attn_out, ctx);

    fc_kernel<<<dim3(32, 16), 256, 0, stream>>>(ctx, wfcb, dyn_out);
}

// Round 18
// 170.493 us; speedup vs baseline: 1.1602x; 1.1602x over previous
//
#include <hip/hip_runtime.h>
#include <hip/hip_bf16.h>

#define B_ 4
#define L_ 1024
#define D_ 1024
#define H_ 16
#define NROWS_ (B_ * L_)   // 4096

typedef __attribute__((ext_vector_type(8))) short short8;
typedef __attribute__((ext_vector_type(4))) float f32x4;

__device__ __forceinline__ ushort f2bf(float f) {   // native RNE cvt (single VALU op)
    __hip_bfloat16 h = __float2bfloat16(f);
    return *reinterpret_cast<ushort*>(&h);
}
__device__ __forceinline__ float bf2f(ushort u) {
    union { uint u; float f; } x; x.u = (uint)u << 16; return x.f;
}
__device__ __forceinline__ void gl_lds16(const void* g, void* l) {
    __builtin_amdgcn_global_load_lds(
        (const __attribute__((address_space(1))) uint*)(uintptr_t)g,
        (__attribute__((address_space(3))) uint*)(uintptr_t)l, 16, 0, 0);
}

#define EXP2C 0.1803368801111244f   // 0.125 * log2(e), baked into qh projection

// ---------------- fused LayerNorm->bf16  +  weight cvt ----------------
__global__ __launch_bounds__(256) void lnwcvt_kernel(
    const float* __restrict__ q, const float* __restrict__ k, const float* __restrict__ v,
    const float* __restrict__ ln1w, const float* __restrict__ ln1b,
    const float* __restrict__ ln2w, const float* __restrict__ ln2b,
    const float* __restrict__ ln3w, const float* __restrict__ ln3b,
    ushort* __restrict__ qn, ushort* __restrict__ kn, ushort* __restrict__ vn,
    const float* __restrict__ wq, const float* __restrict__ wk,
    const float* __restrict__ wv, const float* __restrict__ wfc,
    ushort* __restrict__ wqb, ushort* __restrict__ wkb,
    ushort* __restrict__ wvb, ushort* __restrict__ wfcb)
{
    const int bid = blockIdx.x, t = threadIdx.x;
    if (bid >= 12288) {   // weight convert (read-once: NT loads via ext_vector)
        const int wbid = bid - 12288;
        const int which = wbid >> 10;
        const float* src = which == 0 ? wq : which == 1 ? wk : which == 2 ? wv : wfc;
        ushort* dst      = which == 0 ? wqb : which == 1 ? wkb : which == 2 ? wvb : wfcb;
        const size_t i = (size_t)(wbid & 1023) * 256 + t;
        const f32x4 f = __builtin_nontemporal_load(&((const f32x4*)src)[i]);
        ushort4 o; o.x = f2bf(f[0]); o.y = f2bf(f[1]); o.z = f2bf(f[2]); o.w = f2bf(f[3]);
        ((ushort4*)dst)[i] = o;
        return;
    }
    const int which = bid >> 12, row = bid & 4095;
    const float *x, *lw, *lb; ushort* out;
    if (which == 0)      { x = q; lw = ln1w; lb = ln1b; out = qn; }
    else if (which == 1) { x = k; lw = ln2w; lb = ln2b; out = kn; }
    else                 { x = v; lw = ln3w; lb = ln3b; out = vn; }
    x += (size_t)row * D_; out += (size_t)row * D_;
    const f32x4 t4 = __builtin_nontemporal_load(&((const f32x4*)x)[t]);
    float s  = t4[0] + t4[1] + t4[2] + t4[3];
    float s2 = t4[0]*t4[0] + t4[1]*t4[1] + t4[2]*t4[2] + t4[3]*t4[3];
    #pragma unroll
    for (int off = 1; off < 64; off <<= 1) {
        s  += __shfl_xor(s,  off, 64);
        s2 += __shfl_xor(s2, off, 64);
    }
    __shared__ float red[8];
    __shared__ float mr[2];
    const int wid = t >> 6;
    if ((t & 63) == 0) { red[wid*2] = s; red[wid*2+1] = s2; }
    __syncthreads();
    if (t == 0) {
        s  = red[0] + red[2] + red[4] + red[6];
        s2 = red[1] + red[3] + red[5] + red[7];
        const float mean = s * (1.0f/(float)D_);
        const float var  = s2 * (1.0f/(float)D_) - mean*mean;
        mr[0] = mean; mr[1] = rsqrtf(var + 1e-5f);
    }
    __syncthreads();
    const float mean = mr[0], rstd = mr[1];
    const float4 w4 = ((const float4*)lw)[t];
    const float4 b4 = ((const float4*)lb)[t];
    ushort4 o;
    o.x = f2bf((t4[0] - mean)*rstd*w4.x + b4.x);
    o.y = f2bf((t4[1] - mean)*rstd*w4.y + b4.y);
    o.z = f2bf((t4[2] - mean)*rstd*w4.z + b4.z);
    o.w = f2bf((t4[3] - mean)*rstd*w4.w + b4.w);
    ((ushort4*)out)[t] = o;
}

// ---------------- fused mask gather (first) + 3-way projection GEMM ----------------
__global__ __launch_bounds__(256) void projgather_kernel(
    const ushort* __restrict__ qn, const ushort* __restrict__ kn, const ushort* __restrict__ vn,
    const ushort* __restrict__ wqb, const ushort* __restrict__ wkb, const ushort* __restrict__ wvb,
    ushort* __restrict__ qh, ushort* __restrict__ kh, ushort* __restrict__ vtw,
    const int* __restrict__ mask, uint2* __restrict__ gbits)
{
    const int gid = blockIdx.x;
    const int t = threadIdx.x;
    if (gid < 256) {    // mask gather: 16 rows per block (dispatches FIRST, hides under GEMM)
        const int row = gid * 16 + (t >> 4);
        const int lc = t & 15;
        const int* src = mask + (size_t)row * 1024 + lc;
        uint lo = 0, hi = 0;
        #pragma unroll
        for (int j = 0; j < 32; j++) lo |= (__builtin_nontemporal_load(&src[16*j])      != 0 ? 1u : 0u) << j;
        #pragma unroll
        for (int j = 0; j < 32; j++) hi |= (__builtin_nontemporal_load(&src[16*(j+32)]) != 0 ? 1u : 0u) << j;
        gbits[(size_t)row*16 + lc] = make_uint2(lo, hi);
        return;
    }
    __shared__ __align__(16) ushort As[128*64];
    __shared__ __align__(16) ushort Bs[128*64];
    const int gg = gid - 256;
    const int z = gg % 3, id = gg / 3;
    const ushort *A, *W; ushort* out;
    if (z == 0)      { A = qn;  W = wqb; out = qh;  }
    else if (z == 1) { A = kn;  W = wkb; out = kh;  }
    else             { A = wvb; W = vn;  out = vtw; }
    int bm, bn;
    if (z < 2) { bm = (id >> 3) * 128; bn = (id & 7)  * 128; }
    else       { bm = (id >> 5) * 128; bn = (id & 31) * 128; }

    const int w = t >> 6, lane = t & 63;
    const int lc = lane & 15, g = lane >> 4;
    const int wr = w >> 1, wc = w & 1;
    const int srow = lane >> 3, sp = lane & 7;
    f32x4 acc[4][4] = {};

    for (int k0 = 0; k0 < 1024; k0 += 64) {
        #pragma unroll
        for (int j = 0; j < 4; j++) {
            const int i = w*4 + j;
            const int row = i*8 + srow;
            const int c = (sp - (row & 7)) & 7;
            gl_lds16(A + (size_t)(bm+row)*1024 + k0 + c*8, &As[i*512]);
            gl_lds16(W + (size_t)(bn+row)*1024 + k0 + c*8, &Bs[i*512]);
        }
        __syncthreads();
        #pragma unroll
        for (int ks = 0; ks < 2; ks++) {
            short8 af[4], bf4[4];
            #pragma unroll
            for (int mi = 0; mi < 4; mi++) {
                const int row = wr*64 + mi*16 + lc;
                af[mi] = *(const short8*)&As[row*64 + (((ks*4+g) + (row&7)) & 7)*8];
            }
            #pragma unroll
            for (int ni = 0; ni < 4; ni++) {
                const int row = wc*64 + ni*16 + lc;
                bf4[ni] = *(const short8*)&Bs[row*64 + (((ks*4+g) + (row&7)) & 7)*8];
            }
            #pragma unroll
            for (int mi = 0; mi < 4; mi++)
                #pragma unroll
                for (int ni = 0; ni < 4; ni++)
                    acc[mi][ni] = __builtin_amdgcn_mfma_f32_16x16x32_bf16(af[mi], bf4[ni], acc[mi][ni], 0, 0, 0);
        }
        __syncthreads();
    }

    const float scale = (z == 0) ? EXP2C : 1.0f;   // bake softmax scale into qh
    #pragma unroll
    for (int mi = 0; mi < 4; mi++)
        #pragma unroll
        for (int ni = 0; ni < 4; ni++)
            #pragma unroll
            for (int r = 0; r < 4; r++) {
                const int m = bm + wr*64 + mi*16 + g*4 + r;
                const int n = bn + wc*64 + ni*16 + lc;
                const ushort val = f2bf(acc[mi][ni][r] * scale);
                if (z < 2) {
                    const int bb = m >> 10, seq = m & 1023, hh = n >> 6, d = n & 63;
                    out[(((size_t)(bb*16+hh))*1024 + seq)*64 + d] = val;
                } else {
                    const int bb = n >> 10, seq = n & 1023, hh = m >> 6, d = m & 63;
                    out[((size_t)(bb*16+hh))*65536 + (size_t)d*1024 + seq] = val;
                }
            }
}

// ---------------- fc GEMM: 128x64 tile, fp32 NT out ----------------
__global__ __launch_bounds__(256) void fc_kernel(
    const ushort* __restrict__ A, const ushort* __restrict__ W, float* __restrict__ C)
{
    __shared__ __align__(16) ushort As[128*64];
    __shared__ __align__(16) ushort Bs[64*64];
    const int t = threadIdx.x, w = t >> 6, lane = t & 63;
    const int lc = lane & 15, g = lane >> 4;
    const int wr = w >> 1, wc = w & 1;
    const int bm = blockIdx.x * 128, bn = blockIdx.y * 64;
    const int srow = lane >> 3, sp = lane & 7;
    f32x4 acc[4][2] = {};

    for (int k0 = 0; k0 < 1024; k0 += 64) {
        #pragma unroll
        for (int j = 0; j < 4; j++) {
            const int i = w*4 + j;
            const int row = i*8 + srow;
            const int c = (sp - (row & 7)) & 7;
            gl_lds16(A + (size_t)(bm+row)*1024 + k0 + c*8, &As[i*512]);
        }
        #pragma unroll
        for (int j = 0; j < 2; j++) {
            const int i = w*2 + j;
            const int row = i*8 + srow;
            const int c = (sp - (row & 7)) & 7;
            gl_lds16(W + (size_t)(bn+row)*1024 + k0 + c*8, &Bs[i*512]);
        }
        __syncthreads();
        #pragma unroll
        for (int ks = 0; ks < 2; ks++) {
            short8 af[4], bf4[2];
            #pragma unroll
            for (int mi = 0; mi < 4; mi++) {
                const int row = wr*64 + mi*16 + lc;
                af[mi] = *(const short8*)&As[row*64 + (((ks*4+g) + (row&7)) & 7)*8];
            }
            #pragma unroll
            for (int ni = 0; ni < 2; ni++) {
                const int row = wc*32 + ni*16 + lc;
                bf4[ni] = *(const short8*)&Bs[row*64 + (((ks*4+g) + (row&7)) & 7)*8];
            }
            #pragma unroll
            for (int mi = 0; mi < 4; mi++)
                #pragma unroll
                for (int ni = 0; ni < 2; ni++)
                    acc[mi][ni] = __builtin_amdgcn_mfma_f32_16x16x32_bf16(af[mi], bf4[ni], acc[mi][ni], 0, 0, 0);
        }
        __syncthreads();
    }

    #pragma unroll
    for (int mi = 0; mi < 4; mi++)
        #pragma unroll
        for (int ni = 0; ni < 2; ni++)
            #pragma unroll
            for (int r = 0; r < 4; r++)
                __builtin_nontemporal_store(acc[mi][ni][r],
                    &C[(size_t)(bm + wr*64 + mi*16 + g*4 + r)*1024 + bn + wc*32 + ni*16 + lc]);
}

// ---------------- MFMA attention: 8 waves, 128 q-rows/block, XCD-grouped ----------------
// Round-16 configuration restored: Pb round-trip + invL + 4x line-coalesced NT dwordx4 p-stores.
#define AS_VMCNT(N) asm volatile("s_waitcnt vmcnt(" #N ")" ::: "memory")
#define AS_BAR()    asm volatile("s_barrier" ::: "memory")

__global__ __launch_bounds__(512, 4) void attn_kernel(
    const ushort* __restrict__ qh, const ushort* __restrict__ kh, const ushort* __restrict__ vt,
    const uint2* __restrict__ gbits, float* __restrict__ p_out, ushort* __restrict__ ctx)
{
    __shared__ __align__(16) ushort KV[6][64*64];   // [0..2]=K triple buf; [3..5]=V triple buf
    __shared__ __align__(16) ushort Pb[8][16*72];
    __shared__ float invL[8][16];
    const int t = threadIdx.x, w = t >> 6, lane = t & 63;
    const int lc = lane & 15, g = lane >> 4;
    // XCD-aware decode
    const int p = blockIdx.x;
    const int xcd = p & 7, slot = p >> 3;
    const int grp = xcd + 8 * (slot >> 3);       // 0..63
    const int tile = slot & 7;
    const int h = grp & 15, b = grp >> 4;
    const int q0 = tile * 128;
    const int qrow = w * 16;
    const ushort* qbase = qh + ((size_t)(b*16+h)*1024 + q0 + qrow)*64;
    const ushort* kbase = kh + (size_t)(b*16+h)*1024*64;
    const ushort* vbase = vt + (size_t)(b*16+h)*64*1024;
    ushort* PbW = Pb[w];

    // Q fragments (EXP2C pre-baked by projection)
    const short8 aq0 = *(const short8*)(qbase + (size_t)lc*64 + g*8);
    const short8 aq1 = *(const short8*)(qbase + (size_t)lc*64 + 32 + g*8);

    // gathered mask bits: 4 q-rows per thread, bit (kt*4+ni) = masked
    unsigned long long gb[4];
    #pragma unroll
    for (int r = 0; r < 4; r++) {
        const uint2 u = gbits[((size_t)(b*1024 + q0 + qrow + g*4 + r))*16 + lc];
        gb[r] = ((unsigned long long)u.y << 32) | (unsigned long long)u.x;
    }

    // staging geometry
    const int srow = t >> 3;                     // 0..63
    const int sp = t & 7;
    const int c = (sp - (srow & 7)) & 7;

    // prologue: K tile 0 -> KV[0]
    gl_lds16(kbase + (size_t)srow*64 + c*8, &KV[0][w*512]);

    float s_part[4] = {0.f, 0.f, 0.f, 0.f};

    // ---- pass 1: row sums of exp2(S), K triple-buffered, ONE barrier/iter ----
    for (int kt = 0; kt < 16; kt++) {
        const ushort* kcur = KV[kt % 3];
        if (kt < 15) {
            gl_lds16(kbase + ((size_t)((kt+1)*64+srow))*64 + c*8, &KV[(kt+1)%3][w*512]);
            AS_VMCNT(1);
        } else {
            AS_VMCNT(0);
        }
        AS_BAR();
        f32x4 sacc[4];
        __builtin_amdgcn_s_setprio(1);
        #pragma unroll
        for (int ni = 0; ni < 4; ni++) {
            const int row = ni*16 + lc;
            const short8 b0 = *(const short8*)&kcur[row*64 + (((g  ) + (row&7)) & 7)*8];
            const short8 b1 = *(const short8*)&kcur[row*64 + (((4+g) + (row&7)) & 7)*8];
            f32x4 z = {0.f,0.f,0.f,0.f};
            z = __builtin_amdgcn_mfma_f32_16x16x32_bf16(aq0, b0, z, 0, 0, 0);
            z = __builtin_amdgcn_mfma_f32_16x16x32_bf16(aq1, b1, z, 0, 0, 0);
            sacc[ni] = z;
        }
        __builtin_amdgcn_s_setprio(0);
        #pragma unroll
        for (int r = 0; r < 4; r++) {
            const uint mb = (uint)(gb[r] >> (kt*4)) & 15u;   // hoisted nibble
            #pragma unroll
            for (int ni = 0; ni < 4; ni++) {
                const bool mk = (mb >> ni) & 1u;
                s_part[r] += mk ? 0.f : exp2f(sacc[ni][r]);
            }
        }
        // no trailing barrier: 3-buffer distance-2 safety
    }

    // prefetch pass-2 tile 0: K -> KV[1], V -> KV[4]
    gl_lds16(kbase + (size_t)srow*64 + c*8,   &KV[1][w*512]);
    gl_lds16(vbase + (size_t)srow*1024 + c*8, &KV[4][w*512]);

    float inv[4];
    #pragma unroll
    for (int r = 0; r < 4; r++) {
        float s = s_part[r];
        #pragma unroll
        for (int off = 1; off < 16; off <<= 1) s += __shfl_xor(s, off, 64);
        inv[r] = (s > 0.f) ? (1.0f / s) : 0.f;
        if (lc == 0) invL[w][g*4 + r] = inv[r];   // per-wave inv table for p-write lanes
    }
    asm volatile("s_waitcnt lgkmcnt(0)" ::: "memory");

    // ---- pass 2: Pb holds RAW bf16(e); PV unnormalized; inv applied at p-write & epilogue ----
    f32x4 cacc[4] = {{0,0,0,0},{0,0,0,0},{0,0,0,0},{0,0,0,0}};
    float* pblk = p_out + ((size_t)(h*B_ + b)*1024 + q0 + qrow)*1024;
    const int prow = lane >> 4;            // p-write: 0..3
    const int pcol = (lane & 15) * 4;      // p-write: 0..60
    for (int kt = 0; kt < 16; kt++) {
        const int kb = (kt + 1) % 3;
        const ushort* kcur = KV[kb];
        const ushort* vcur = KV[3 + kb];
        if (kt < 15) {
            const int nb = (kt + 2) % 3;
            gl_lds16(kbase + ((size_t)((kt+1)*64+srow))*64 + c*8, &KV[nb][w*512]);
            gl_lds16(vbase + (size_t)srow*1024 + (kt+1)*64 + c*8, &KV[3+nb][w*512]);
        }
        if (kt == 0) { AS_VMCNT(2); } else if (kt == 15) { AS_VMCNT(4); } else { AS_VMCNT(6); }
        AS_BAR();
        f32x4 sacc[4];
        __builtin_amdgcn_s_setprio(1);
        #pragma unroll
        for (int ni = 0; ni < 4; ni++) {
            const int row = ni*16 + lc;
            const short8 b0 = *(const short8*)&kcur[row*64 + (((g  ) + (row&7)) & 7)*8];
            const short8 b1 = *(const short8*)&kcur[row*64 + (((4+g) + (row&7)) & 7)*8];
            f32x4 z = {0.f,0.f,0.f,0.f};
            z = __builtin_amdgcn_mfma_f32_16x16x32_bf16(aq0, b0, z, 0, 0, 0);
            z = __builtin_amdgcn_mfma_f32_16x16x32_bf16(aq1, b1, z, 0, 0, 0);
            sacc[ni] = z;
        }
        __builtin_amdgcn_s_setprio(0);
        #pragma unroll
        for (int r = 0; r < 4; r++) {
            const uint mb = (uint)(gb[r] >> (kt*4)) & 15u;
            #pragma unroll
            for (int ni = 0; ni < 4; ni++) {
                const bool mk = (mb >> ni) & 1u;
                const float e = mk ? 0.f : exp2f(sacc[ni][r]);
                PbW[(g*4+r)*72 + ni*16 + lc] = f2bf(e);      // raw e, no inv mul
            }
        }
        {   // line-coalesced NT p write: instr s covers rows 4s..4s+3, 256B contiguous per row
            #pragma unroll
            for (int s = 0; s < 4; s++) {
                const int row = s*4 + prow;
                const float iv = invL[w][row];
                const ushort4 ev = *(const ushort4*)&PbW[row*72 + pcol];
                f32x4 o;
                o[0] = bf2f(ev.x)*iv; o[1] = bf2f(ev.y)*iv;
                o[2] = bf2f(ev.z)*iv; o[3] = bf2f(ev.w)*iv;
                __builtin_nontemporal_store(o, (f32x4*)(pblk + (size_t)row*1024 + kt*64 + pcol));
            }
        }
        const short8 pa0 = *(const short8*)&PbW[lc*72 + g*8];
        const short8 pa1 = *(const short8*)&PbW[lc*72 + 32 + g*8];
        __builtin_amdgcn_s_setprio(1);
        #pragma unroll
        for (int di = 0; di < 4; di++) {
            const int row = di*16 + lc;
            const short8 vb0 = *(const short8*)&vcur[row*64 + (((g  ) + (row&7)) & 7)*8];
            const short8 vb1 = *(const short8*)&vcur[row*64 + (((4+g) + (row&7)) & 7)*8];
            cacc[di] = __builtin_amdgcn_mfma_f32_16x16x32_bf16(pa0, vb0, cacc[di], 0, 0, 0);
            cacc[di] = __builtin_amdgcn_mfma_f32_16x16x32_bf16(pa1, vb1, cacc[di], 0, 0, 0);
        }
        __builtin_amdgcn_s_setprio(0);
        // no trailing barrier: 3-buffer distance-2 safety
    }

    // ---- ctx epilogue: normalize (PV was on raw e), transpose through PbW ----
    #pragma unroll
    for (int di = 0; di < 4; di++)
        #pragma unroll
        for (int r = 0; r < 4; r++)
            PbW[(g*4+r)*72 + di*16 + lc] = f2bf(cacc[di][r] * inv[r]);
    {
        const int rr = lane >> 2, seg = (lane & 3) * 16;
        const short8 c0 = *(const short8*)&PbW[rr*72 + seg + 0];
        const short8 c1 = *(const short8*)&PbW[rr*72 + seg + 8];
        ushort* dst = ctx + ((size_t)(b*1024 + q0 + qrow + rr))*1024 + h*64 + seg;
        *(short8*)(dst + 0) = c0;
        *(short8*)(dst + 8) = c1;
    }
}

extern "C" void kernel_launch(void* const* d_in, const int* in_sizes, int n_in,
                              void* d_out, int out_size, void* d_ws, size_t ws_size,
                              hipStream_t stream)
{
    const float* q    = (const float*)d_in[0];
    const float* k    = (const float*)d_in[1];
    const float* v    = (const float*)d_in[2];
    const int*   mask = (const int*)d_in[4];
    const float* ln1w = (const float*)d_in[5];
    const float* ln1b = (const float*)d_in[6];
    const float* ln2w = (const float*)d_in[7];
    const float* ln2b = (const float*)d_in[8];
    const float* ln3w = (const float*)d_in[9];
    const float* ln3b = (const float*)d_in[10];
    const float* wq   = (const float*)d_in[11];
    const float* wk   = (const float*)d_in[12];
    const float* wv   = (const float*)d_in[13];
    const float* wfc  = (const float*)d_in[14];

    float* dyn_out  = (float*)d_out;                       // [B, L, D]
    float* attn_out = dyn_out + (size_t)B_ * L_ * D_;      // [H*B, L, L]

    char* ws = (char*)d_ws;
    uint2*  gbits = (uint2*)ws;       ws += (size_t)NROWS_ * 16 * 8;         // 512 KB
    ushort* qn    = (ushort*)ws;      ws += (size_t)NROWS_ * D_ * 2;
    ushort* kn    = (ushort*)ws;      ws += (size_t)NROWS_ * D_ * 2;
    ushort* vn    = (ushort*)ws;      ws += (size_t)NROWS_ * D_ * 2;
    ushort* wqb   = (ushort*)ws;      ws += (size_t)D_ * D_ * 2;
    ushort* wkb   = (ushort*)ws;      ws += (size_t)D_ * D_ * 2;
    ushort* wvb   = (ushort*)ws;      ws += (size_t)D_ * D_ * 2;
    ushort* wfcb  = (ushort*)ws;      ws += (size_t)D_ * D_ * 2;
    ushort* qh    = (ushort*)ws;      ws += (size_t)NROWS_ * D_ * 2;
    ushort* kh    = (ushort*)ws;      ws += (size_t)NROWS_ * D_ * 2;
    ushort* vtw   = (ushort*)ws;      ws += (size_t)NROWS_ * D_ * 2;
    ushort* ctx   = qn;               // qn dead after proj; reuse

    lnwcvt_kernel<<<16384, 256, 0, stream>>>(q, k, v, ln1w, ln1b, ln2w, ln2b, ln3w, ln3b,
                                             qn, kn, vn, wq, wk, wv, wfc, wqb, wkb, wvb, wfcb);

    projgather_kernel<<<1024, 256, 0, stream>>>(qn, kn, vn, wqb, wkb, wvb, qh, kh, vtw, mask, gbits);

    attn_kernel<<<512, 512, 0, stream>>>(qh, kh, vtw, gbits, attn_out, ctx);

    fc_kernel<<<dim3(32, 16), 256, 0, stream>>>(ctx, wfcb, dyn_out);
}

// Round 19
// 169.123 us; speedup vs baseline: 1.1696x; 1.0081x over previous
//
#include <hip/hip_runtime.h>
#include <hip/hip_bf16.h>

#define B_ 4
#define L_ 1024
#define D_ 1024
#define H_ 16
#define NROWS_ (B_ * L_)   // 4096

typedef __attribute__((ext_vector_type(8))) short short8;
typedef __attribute__((ext_vector_type(4))) float f32x4;

__device__ __forceinline__ ushort f2bf(float f) {   // native RNE cvt (single VALU op)
    __hip_bfloat16 h = __float2bfloat16(f);
    return *reinterpret_cast<ushort*>(&h);
}
__device__ __forceinline__ float bf2f(ushort u) {
    union { uint u; float f; } x; x.u = (uint)u << 16; return x.f;
}
__device__ __forceinline__ void gl_lds16(const void* g, void* l) {
    __builtin_amdgcn_global_load_lds(
        (const __attribute__((address_space(1))) uint*)(uintptr_t)g,
        (__attribute__((address_space(3))) uint*)(uintptr_t)l, 16, 0, 0);
}

#define EXP2C 0.1803368801111244f   // 0.125 * log2(e), baked into qh projection

// ---------------- fused LayerNorm->bf16  +  weight cvt ----------------
__global__ __launch_bounds__(256) void lnwcvt_kernel(
    const float* __restrict__ q, const float* __restrict__ k, const float* __restrict__ v,
    const float* __restrict__ ln1w, const float* __restrict__ ln1b,
    const float* __restrict__ ln2w, const float* __restrict__ ln2b,
    const float* __restrict__ ln3w, const float* __restrict__ ln3b,
    ushort* __restrict__ qn, ushort* __restrict__ kn, ushort* __restrict__ vn,
    const float* __restrict__ wq, const float* __restrict__ wk,
    const float* __restrict__ wv, const float* __restrict__ wfc,
    ushort* __restrict__ wqb, ushort* __restrict__ wkb,
    ushort* __restrict__ wvb, ushort* __restrict__ wfcb)
{
    const int bid = blockIdx.x, t = threadIdx.x;
    if (bid >= 12288) {   // weight convert (read-once: NT loads via ext_vector)
        const int wbid = bid - 12288;
        const int which = wbid >> 10;
        const float* src = which == 0 ? wq : which == 1 ? wk : which == 2 ? wv : wfc;
        ushort* dst      = which == 0 ? wqb : which == 1 ? wkb : which == 2 ? wvb : wfcb;
        const size_t i = (size_t)(wbid & 1023) * 256 + t;
        const f32x4 f = __builtin_nontemporal_load(&((const f32x4*)src)[i]);
        ushort4 o; o.x = f2bf(f[0]); o.y = f2bf(f[1]); o.z = f2bf(f[2]); o.w = f2bf(f[3]);
        ((ushort4*)dst)[i] = o;
        return;
    }
    const int which = bid >> 12, row = bid & 4095;
    const float *x, *lw, *lb; ushort* out;
    if (which == 0)      { x = q; lw = ln1w; lb = ln1b; out = qn; }
    else if (which == 1) { x = k; lw = ln2w; lb = ln2b; out = kn; }
    else                 { x = v; lw = ln3w; lb = ln3b; out = vn; }
    x += (size_t)row * D_; out += (size_t)row * D_;
    const f32x4 t4 = __builtin_nontemporal_load(&((const f32x4*)x)[t]);
    float s  = t4[0] + t4[1] + t4[2] + t4[3];
    float s2 = t4[0]*t4[0] + t4[1]*t4[1] + t4[2]*t4[2] + t4[3]*t4[3];
    #pragma unroll
    for (int off = 1; off < 64; off <<= 1) {
        s  += __shfl_xor(s,  off, 64);
        s2 += __shfl_xor(s2, off, 64);
    }
    __shared__ float red[8];
    __shared__ float mr[2];
    const int wid = t >> 6;
    if ((t & 63) == 0) { red[wid*2] = s; red[wid*2+1] = s2; }
    __syncthreads();
    if (t == 0) {
        s  = red[0] + red[2] + red[4] + red[6];
        s2 = red[1] + red[3] + red[5] + red[7];
        const float mean = s * (1.0f/(float)D_);
        const float var  = s2 * (1.0f/(float)D_) - mean*mean;
        mr[0] = mean; mr[1] = rsqrtf(var + 1e-5f);
    }
    __syncthreads();
    const float mean = mr[0], rstd = mr[1];
    const float4 w4 = ((const float4*)lw)[t];
    const float4 b4 = ((const float4*)lb)[t];
    ushort4 o;
    o.x = f2bf((t4[0] - mean)*rstd*w4.x + b4.x);
    o.y = f2bf((t4[1] - mean)*rstd*w4.y + b4.y);
    o.z = f2bf((t4[2] - mean)*rstd*w4.z + b4.z);
    o.w = f2bf((t4[3] - mean)*rstd*w4.w + b4.w);
    ((ushort4*)out)[t] = o;
}

// ---------------- fused mask gather + XCD-clustered 3-way projection GEMM ----------------
// gid < 256: mask gather. gid >= 256: GEMM with XCD-aware decode:
//   gg = gid-256; xcd = gg&7; s = gg>>3 (96 slots/XCD); z = s/32; j = s%32.
//   z<2:  bm-block = xcd + 8*(j>>3) (4 A-panels/XCD), bn-block = j&7  -> A 1MB + W 2MB resident/XCD
//   z==2: d-block  = xcd (wv-panel resident), bn-block = j (vn streamed)
__global__ __launch_bounds__(256) void projgather_kernel(
    const ushort* __restrict__ qn, const ushort* __restrict__ kn, const ushort* __restrict__ vn,
    const ushort* __restrict__ wqb, const ushort* __restrict__ wkb, const ushort* __restrict__ wvb,
    ushort* __restrict__ qh, ushort* __restrict__ kh, ushort* __restrict__ vtw,
    const int* __restrict__ mask, uint2* __restrict__ gbits)
{
    const int gid = blockIdx.x;
    const int t = threadIdx.x;
    if (gid < 256) {    // mask gather: 16 rows per block (dispatches first, hides under GEMM)
        const int row = gid * 16 + (t >> 4);
        const int lc = t & 15;
        const int* src = mask + (size_t)row * 1024 + lc;
        uint lo = 0, hi = 0;
        #pragma unroll
        for (int j = 0; j < 32; j++) lo |= (__builtin_nontemporal_load(&src[16*j])      != 0 ? 1u : 0u) << j;
        #pragma unroll
        for (int j = 0; j < 32; j++) hi |= (__builtin_nontemporal_load(&src[16*(j+32)]) != 0 ? 1u : 0u) << j;
        gbits[(size_t)row*16 + lc] = make_uint2(lo, hi);
        return;
    }
    __shared__ __align__(16) ushort As[128*64];
    __shared__ __align__(16) ushort Bs[128*64];
    const int gg = gid - 256;
    const int xcd = gg & 7, sl = gg >> 3;
    const int z = sl >> 5, j = sl & 31;
    const ushort *A, *W; ushort* out;
    if (z == 0)      { A = qn;  W = wqb; out = qh;  }
    else if (z == 1) { A = kn;  W = wkb; out = kh;  }
    else             { A = wvb; W = vn;  out = vtw; }
    int bm, bn;
    if (z < 2) { bm = (xcd + 8*(j >> 3)) * 128; bn = (j & 7) * 128; }
    else       { bm = xcd * 128;                bn = j * 128;       }

    const int w = t >> 6, lane = t & 63;
    const int lc = lane & 15, g = lane >> 4;
    const int wr = w >> 1, wc = w & 1;
    const int srow = lane >> 3, sp = lane & 7;
    f32x4 acc[4][4] = {};

    for (int k0 = 0; k0 < 1024; k0 += 64) {
        #pragma unroll
        for (int jj = 0; jj < 4; jj++) {
            const int i = w*4 + jj;
            const int row = i*8 + srow;
            const int c = (sp - (row & 7)) & 7;
            gl_lds16(A + (size_t)(bm+row)*1024 + k0 + c*8, &As[i*512]);
            gl_lds16(W + (size_t)(bn+row)*1024 + k0 + c*8, &Bs[i*512]);
        }
        __syncthreads();
        #pragma unroll
        for (int ks = 0; ks < 2; ks++) {
            short8 af[4], bf4[4];
            #pragma unroll
            for (int mi = 0; mi < 4; mi++) {
                const int row = wr*64 + mi*16 + lc;
                af[mi] = *(const short8*)&As[row*64 + (((ks*4+g) + (row&7)) & 7)*8];
            }
            #pragma unroll
            for (int ni = 0; ni < 4; ni++) {
                const int row = wc*64 + ni*16 + lc;
                bf4[ni] = *(const short8*)&Bs[row*64 + (((ks*4+g) + (row&7)) & 7)*8];
            }
            #pragma unroll
            for (int mi = 0; mi < 4; mi++)
                #pragma unroll
                for (int ni = 0; ni < 4; ni++)
                    acc[mi][ni] = __builtin_amdgcn_mfma_f32_16x16x32_bf16(af[mi], bf4[ni], acc[mi][ni], 0, 0, 0);
        }
        __syncthreads();
    }

    const float scale = (z == 0) ? EXP2C : 1.0f;   // bake softmax scale into qh
    #pragma unroll
    for (int mi = 0; mi < 4; mi++)
        #pragma unroll
        for (int ni = 0; ni < 4; ni++)
            #pragma unroll
            for (int r = 0; r < 4; r++) {
                const int m = bm + wr*64 + mi*16 + g*4 + r;
                const int n = bn + wc*64 + ni*16 + lc;
                const ushort val = f2bf(acc[mi][ni][r] * scale);
                if (z < 2) {
                    const int bb = m >> 10, seq = m & 1023, hh = n >> 6, d = n & 63;
                    out[(((size_t)(bb*16+hh))*1024 + seq)*64 + d] = val;
                } else {
                    const int bb = n >> 10, seq = n & 1023, hh = m >> 6, d = m & 63;
                    out[((size_t)(bb*16+hh))*65536 + (size_t)d*1024 + seq] = val;
                }
            }
}

// ---------------- fc GEMM: 128x64 tile, fp32 NT out ----------------
__global__ __launch_bounds__(256) void fc_kernel(
    const ushort* __restrict__ A, const ushort* __restrict__ W, float* __restrict__ C)
{
    __shared__ __align__(16) ushort As[128*64];
    __shared__ __align__(16) ushort Bs[64*64];
    const int t = threadIdx.x, w = t >> 6, lane = t & 63;
    const int lc = lane & 15, g = lane >> 4;
    const int wr = w >> 1, wc = w & 1;
    const int bm = blockIdx.x * 128, bn = blockIdx.y * 64;
    const int srow = lane >> 3, sp = lane & 7;
    f32x4 acc[4][2] = {};

    for (int k0 = 0; k0 < 1024; k0 += 64) {
        #pragma unroll
        for (int j = 0; j < 4; j++) {
            const int i = w*4 + j;
            const int row = i*8 + srow;
            const int c = (sp - (row & 7)) & 7;
            gl_lds16(A + (size_t)(bm+row)*1024 + k0 + c*8, &As[i*512]);
        }
        #pragma unroll
        for (int j = 0; j < 2; j++) {
            const int i = w*2 + j;
            const int row = i*8 + srow;
            const int c = (sp - (row & 7)) & 7;
            gl_lds16(W + (size_t)(bn+row)*1024 + k0 + c*8, &Bs[i*512]);
        }
        __syncthreads();
        #pragma unroll
        for (int ks = 0; ks < 2; ks++) {
            short8 af[4], bf4[2];
            #pragma unroll
            for (int mi = 0; mi < 4; mi++) {
                const int row = wr*64 + mi*16 + lc;
                af[mi] = *(const short8*)&As[row*64 + (((ks*4+g) + (row&7)) & 7)*8];
            }
            #pragma unroll
            for (int ni = 0; ni < 2; ni++) {
                const int row = wc*32 + ni*16 + lc;
                bf4[ni] = *(const short8*)&Bs[row*64 + (((ks*4+g) + (row&7)) & 7)*8];
            }
            #pragma unroll
            for (int mi = 0; mi < 4; mi++)
                #pragma unroll
                for (int ni = 0; ni < 2; ni++)
                    acc[mi][ni] = __builtin_amdgcn_mfma_f32_16x16x32_bf16(af[mi], bf4[ni], acc[mi][ni], 0, 0, 0);
        }
        __syncthreads();
    }

    #pragma unroll
    for (int mi = 0; mi < 4; mi++)
        #pragma unroll
        for (int ni = 0; ni < 2; ni++)
            #pragma unroll
            for (int r = 0; r < 4; r++)
                __builtin_nontemporal_store(acc[mi][ni][r],
                    &C[(size_t)(bm + wr*64 + mi*16 + g*4 + r)*1024 + bn + wc*32 + ni*16 + lc]);
}

// ---------------- MFMA attention: 8 waves, 128 q-rows/block, XCD-grouped ----------------
#define AS_VMCNT(N) asm volatile("s_waitcnt vmcnt(" #N ")" ::: "memory")
#define AS_BAR()    asm volatile("s_barrier" ::: "memory")

__global__ __launch_bounds__(512, 4) void attn_kernel(
    const ushort* __restrict__ qh, const ushort* __restrict__ kh, const ushort* __restrict__ vt,
    const uint2* __restrict__ gbits, float* __restrict__ p_out, ushort* __restrict__ ctx)
{
    __shared__ __align__(16) ushort KV[6][64*64];   // [0..2]=K triple buf; [3..5]=V triple buf
    __shared__ __align__(16) ushort Pb[8][16*72];
    __shared__ float invL[8][16];
    const int t = threadIdx.x, w = t >> 6, lane = t & 63;
    const int lc = lane & 15, g = lane >> 4;
    // XCD-aware decode
    const int p = blockIdx.x;
    const int xcd = p & 7, slot = p >> 3;
    const int grp = xcd + 8 * (slot >> 3);       // 0..63
    const int tile = slot & 7;
    const int h = grp & 15, b = grp >> 4;
    const int q0 = tile * 128;
    const int qrow = w * 16;
    const ushort* qbase = qh + ((size_t)(b*16+h)*1024 + q0 + qrow)*64;
    const ushort* kbase = kh + (size_t)(b*16+h)*1024*64;
    const ushort* vbase = vt + (size_t)(b*16+h)*64*1024;
    ushort* PbW = Pb[w];

    // Q fragments (EXP2C pre-baked by projection)
    const short8 aq0 = *(const short8*)(qbase + (size_t)lc*64 + g*8);
    const short8 aq1 = *(const short8*)(qbase + (size_t)lc*64 + 32 + g*8);

    // gathered mask bits: 4 q-rows per thread, bit (kt*4+ni) = masked
    unsigned long long gb[4];
    #pragma unroll
    for (int r = 0; r < 4; r++) {
        const uint2 u = gbits[((size_t)(b*1024 + q0 + qrow + g*4 + r))*16 + lc];
        gb[r] = ((unsigned long long)u.y << 32) | (unsigned long long)u.x;
    }

    // staging geometry
    const int srow = t >> 3;                     // 0..63
    const int sp = t & 7;
    const int c = (sp - (srow & 7)) & 7;

    // prologue: K tile 0 -> KV[0]
    gl_lds16(kbase + (size_t)srow*64 + c*8, &KV[0][w*512]);

    float s_part[4] = {0.f, 0.f, 0.f, 0.f};

    // ---- pass 1: row sums of exp2(S), K triple-buffered, ONE barrier/iter ----
    for (int kt = 0; kt < 16; kt++) {
        const ushort* kcur = KV[kt % 3];
        if (kt < 15) {
            gl_lds16(kbase + ((size_t)((kt+1)*64+srow))*64 + c*8, &KV[(kt+1)%3][w*512]);
            AS_VMCNT(1);
        } else {
            AS_VMCNT(0);
        }
        AS_BAR();
        f32x4 sacc[4];
        __builtin_amdgcn_s_setprio(1);
        #pragma unroll
        for (int ni = 0; ni < 4; ni++) {
            const int row = ni*16 + lc;
            const short8 b0 = *(const short8*)&kcur[row*64 + (((g  ) + (row&7)) & 7)*8];
            const short8 b1 = *(const short8*)&kcur[row*64 + (((4+g) + (row&7)) & 7)*8];
            f32x4 z = {0.f,0.f,0.f,0.f};
            z = __builtin_amdgcn_mfma_f32_16x16x32_bf16(aq0, b0, z, 0, 0, 0);
            z = __builtin_amdgcn_mfma_f32_16x16x32_bf16(aq1, b1, z, 0, 0, 0);
            sacc[ni] = z;
        }
        __builtin_amdgcn_s_setprio(0);
        #pragma unroll
        for (int r = 0; r < 4; r++) {
            const uint mb = (uint)(gb[r] >> (kt*4)) & 15u;   // hoisted nibble
            #pragma unroll
            for (int ni = 0; ni < 4; ni++) {
                const bool mk = (mb >> ni) & 1u;
                s_part[r] += mk ? 0.f : exp2f(sacc[ni][r]);
            }
        }
        // no trailing barrier: 3-buffer distance-2 safety
    }

    // prefetch pass-2 tile 0: K -> KV[1], V -> KV[4]
    gl_lds16(kbase + (size_t)srow*64 + c*8,   &KV[1][w*512]);
    gl_lds16(vbase + (size_t)srow*1024 + c*8, &KV[4][w*512]);

    float inv[4];
    #pragma unroll
    for (int r = 0; r < 4; r++) {
        float s = s_part[r];
        #pragma unroll
        for (int off = 1; off < 16; off <<= 1) s += __shfl_xor(s, off, 64);
        inv[r] = (s > 0.f) ? (1.0f / s) : 0.f;
        if (lc == 0) invL[w][g*4 + r] = inv[r];   // per-wave inv table for p-write lanes
    }
    asm volatile("s_waitcnt lgkmcnt(0)" ::: "memory");

    // ---- pass 2: Pb holds RAW bf16(e); PV unnormalized; inv applied at p-write & epilogue ----
    f32x4 cacc[4] = {{0,0,0,0},{0,0,0,0},{0,0,0,0},{0,0,0,0}};
    float* pblk = p_out + ((size_t)(h*B_ + b)*1024 + q0 + qrow)*1024;
    const int prow = lane >> 4;            // p-write: 0..3
    const int pcol = (lane & 15) * 4;      // p-write: 0..60
    for (int kt = 0; kt < 16; kt++) {
        const int kb = (kt + 1) % 3;
        const ushort* kcur = KV[kb];
        const ushort* vcur = KV[3 + kb];
        if (kt < 15) {
            const int nb = (kt + 2) % 3;
            gl_lds16(kbase + ((size_t)((kt+1)*64+srow))*64 + c*8, &KV[nb][w*512]);
            gl_lds16(vbase + (size_t)srow*1024 + (kt+1)*64 + c*8, &KV[3+nb][w*512]);
        }
        if (kt == 0) { AS_VMCNT(2); } else if (kt == 15) { AS_VMCNT(4); } else { AS_VMCNT(6); }
        AS_BAR();
        f32x4 sacc[4];
        __builtin_amdgcn_s_setprio(1);
        #pragma unroll
        for (int ni = 0; ni < 4; ni++) {
            const int row = ni*16 + lc;
            const short8 b0 = *(const short8*)&kcur[row*64 + (((g  ) + (row&7)) & 7)*8];
            const short8 b1 = *(const short8*)&kcur[row*64 + (((4+g) + (row&7)) & 7)*8];
            f32x4 z = {0.f,0.f,0.f,0.f};
            z = __builtin_amdgcn_mfma_f32_16x16x32_bf16(aq0, b0, z, 0, 0, 0);
            z = __builtin_amdgcn_mfma_f32_16x16x32_bf16(aq1, b1, z, 0, 0, 0);
            sacc[ni] = z;
        }
        __builtin_amdgcn_s_setprio(0);
        #pragma unroll
        for (int r = 0; r < 4; r++) {
            const uint mb = (uint)(gb[r] >> (kt*4)) & 15u;
            #pragma unroll
            for (int ni = 0; ni < 4; ni++) {
                const bool mk = (mb >> ni) & 1u;
                const float e = mk ? 0.f : exp2f(sacc[ni][r]);
                PbW[(g*4+r)*72 + ni*16 + lc] = f2bf(e);      // raw e, no inv mul
            }
        }
        {   // line-coalesced NT p write: instr s covers rows 4s..4s+3, 256B contiguous per row
            #pragma unroll
            for (int s = 0; s < 4; s++) {
                const int row = s*4 + prow;
                const float iv = invL[w][row];
                const ushort4 ev = *(const ushort4*)&PbW[row*72 + pcol];
                f32x4 o;
                o[0] = bf2f(ev.x)*iv; o[1] = bf2f(ev.y)*iv;
                o[2] = bf2f(ev.z)*iv; o[3] = bf2f(ev.w)*iv;
                __builtin_nontemporal_store(o, (f32x4*)(pblk + (size_t)row*1024 + kt*64 + pcol));
            }
        }
        const short8 pa0 = *(const short8*)&PbW[lc*72 + g*8];
        const short8 pa1 = *(const short8*)&PbW[lc*72 + 32 + g*8];
        __builtin_amdgcn_s_setprio(1);
        #pragma unroll
        for (int di = 0; di < 4; di++) {
            const int row = di*16 + lc;
            const short8 vb0 = *(const short8*)&vcur[row*64 + (((g  ) + (row&7)) & 7)*8];
            const short8 vb1 = *(const short8*)&vcur[row*64 + (((4+g) + (row&7)) & 7)*8];
            cacc[di] = __builtin_amdgcn_mfma_f32_16x16x32_bf16(pa0, vb0, cacc[di], 0, 0, 0);
            cacc[di] = __builtin_amdgcn_mfma_f32_16x16x32_bf16(pa1, vb1, cacc[di], 0, 0, 0);
        }
        __builtin_amdgcn_s_setprio(0);
        // no trailing barrier: 3-buffer distance-2 safety
    }

    // ---- ctx epilogue: normalize (PV was on raw e), transpose through PbW ----
    #pragma unroll
    for (int di = 0; di < 4; di++)
        #pragma unroll
        for (int r = 0; r < 4; r++)
            PbW[(g*4+r)*72 + di*16 + lc] = f2bf(cacc[di][r] * inv[r]);
    {
        const int rr = lane >> 2, seg = (lane & 3) * 16;
        const short8 c0 = *(const short8*)&PbW[rr*72 + seg + 0];
        const short8 c1 = *(const short8*)&PbW[rr*72 + seg + 8];
        ushort* dst = ctx + ((size_t)(b*1024 + q0 + qrow + rr))*1024 + h*64 + seg;
        *(short8*)(dst + 0) = c0;
        *(short8*)(dst + 8) = c1;
    }
}

extern "C" void kernel_launch(void* const* d_in, const int* in_sizes, int n_in,
                              void* d_out, int out_size, void* d_ws, size_t ws_size,
                              hipStream_t stream)
{
    const float* q    = (const float*)d_in[0];
    const float* k    = (const float*)d_in[1];
    const float* v    = (const float*)d_in[2];
    const int*   mask = (const int*)d_in[4];
    const float* ln1w = (const float*)d_in[5];
    const float* ln1b = (const float*)d_in[6];
    const float* ln2w = (const float*)d_in[7];
    const float* ln2b = (const float*)d_in[8];
    const float* ln3w = (const float*)d_in[9];
    const float* ln3b = (const float*)d_in[10];
    const float* wq   = (const float*)d_in[11];
    const float* wk   = (const float*)d_in[12];
    const float* wv   = (const float*)d_in[13];
    const float* wfc  = (const float*)d_in[14];

    float* dyn_out  = (float*)d_out;                       // [B, L, D]
    float* attn_out = dyn_out + (size_t)B_ * L_ * D_;      // [H*B, L, L]

    char* ws = (char*)d_ws;
    uint2*  gbits = (uint2*)ws;       ws += (size_t)NROWS_ * 16 * 8;         // 512 KB
    ushort* qn    = (ushort*)ws;      ws += (size_t)NROWS_ * D_ * 2;
    ushort* kn    = (ushort*)ws;      ws += (size_t)NROWS_ * D_ * 2;
    ushort* vn    = (ushort*)ws;      ws += (size_t)NROWS_ * D_ * 2;
    ushort* wqb   = (ushort*)ws;      ws += (size_t)D_ * D_ * 2;
    ushort* wkb   = (ushort*)ws;      ws += (size_t)D_ * D_ * 2;
    ushort* wvb   = (ushort*)ws;      ws += (size_t)D_ * D_ * 2;
    ushort* wfcb  = (ushort*)ws;      ws += (size_t)D_ * D_ * 2;
    ushort* qh    = (ushort*)ws;      ws += (size_t)NROWS_ * D_ * 2;
    ushort* kh    = (ushort*)ws;      ws += (size_t)NROWS_ * D_ * 2;
    ushort* vtw   = (ushort*)ws;      ws += (size_t)NROWS_ * D_ * 2;
    ushort* ctx   = qn;               // qn dead after proj; reuse

    lnwcvt_kernel<<<16384, 256, 0, stream>>>(q, k, v, ln1w, ln1b, ln2w, ln2b, ln3w, ln3b,
                                             qn, kn, vn, wq, wk, wv, wfc, wqb, wkb, wvb, wfcb);

    projgather_kernel<<<1024, 256, 0, stream>>>(qn, kn, vn, wqb, wkb, wvb, qh, kh, vtw, mask, gbits);

    attn_kernel<<<512, 512, 0, stream>>>(qh, kh, vtw, gbits, attn_out, ctx);

    fc_kernel<<<dim3(32, 16), 256, 0, stream>>>(ctx, wfcb, dyn_out);
}